// Round 6
// baseline (1696.204 us; speedup 1.0000x reference)
//
#include <hip/hip_runtime.h>
#include <math.h>

// LotkaVolterra neural-SDE rollout. P=4096, H=256, 100 sequential steps.
// R6 (on R5's register-resident-weights + LDS-buffered-outputs structure):
//  - PB 16 -> 8, grid 512 => 2 independent blocks/CU. One block's MFMA/VALU
//    fills the other block's barrier stalls (per-step critical path is
//    latency/barrier-bound at 1 block/CU: 11k cyc/step vs ~2k of real work).
//  - __launch_bounds__(512,4) caps VGPR at 128 (R5 compiled to exactly 128)
//    so 16 waves/CU co-reside. LDS 49KB/block -> 98KB/CU.
//  - MFMA M=16 with 8 valid paths: rows 8-15 are finite garbage, written to
//    LDS h buffers (sized 16 rows) but never sampled/stored.
//  - prep_weights re-indexed input-side: coalesced fp32 reads, scattered 2B
//    writes (stores don't stall).

#define PP 4096
#define HH 256
#define LT 100
#define PB 8            // valid paths per block (MFMA M=16, rows 8-15 unused)
#define MROWS 16        // MFMA C/D row count
#define SH 264          // bf16 LDS row stride: 528 B (R16=33 odd -> balanced b128 banks)
#define NT 512

typedef __attribute__((ext_vector_type(8))) short short8;
typedef __attribute__((ext_vector_type(4))) short short4v;
typedef __attribute__((ext_vector_type(4))) float float4v;

__device__ __forceinline__ float softplus_f(float x) {
    return fmaxf(x, 0.0f) + log1pf(expf(-fabsf(x)));
}
__device__ __forceinline__ unsigned short f2bf(float f) {   // RNE fp32->bf16
    unsigned int u = __float_as_uint(f);
    u += 0x7fffu + ((u >> 16) & 1u);
    return (unsigned short)(u >> 16);
}
__device__ __forceinline__ float4 ldg4(const float* p) { return *(const float4*)p; }

// ---- prologue: pack weights as bf16 MFMA B-fragments into d_ws ----
// frag layout: wt[m*65536 + ((cg*8+ks)*64+lane)*8+j] = W[(ks*32+(lane>>4)*8+j)*256 + cg*16+(lane&15)]
// W3 region [131072,135168): wt[131072 + (ks*64+lane)*8+j] = W3[k*5+n], n=lane&15 (<5), else 0.
__global__ void prep_weights(const float* __restrict__ W1, const float* __restrict__ W2,
                             const float* __restrict__ W3, unsigned short* __restrict__ wt) {
    const int i = blockIdx.x * 256 + threadIdx.x;
    if (i < 131072) {
        // input-indexed: coalesced read of W[m][k*256+n]
        const int m = i >> 16;            // 0 = W1, 1 = W2
        const int ii = i & 65535;
        const int k = ii >> 8, n = ii & 255;
        const float* W = m ? W2 : W1;
        const float val = W[ii];
        const int ks = k >> 5, quad = (k >> 3) & 3, j = k & 7;
        const int cg = n >> 4, c = n & 15;
        const int lane = quad * 16 + c;
        wt[m * 65536 + ((cg * 8 + ks) * 64 + lane) * 8 + j] = f2bf(val);
    } else if (i < 135168) {
        const int ii = i - 131072;
        const int j = ii & 7, lane = (ii >> 3) & 63, ks = ii >> 9;
        const int k = ks * 32 + (lane >> 4) * 8 + j;
        const int n = lane & 15;
        wt[i] = (n < 5) ? f2bf(W3[k * 5 + n]) : (unsigned short)0;
    }
}

// 256->256 bf16 MFMA layer, B-fragments from registers.
__device__ __forceinline__ void mfma256_reg(const short8 (&wf)[16],
                                            const unsigned short* __restrict__ hin,
                                            unsigned short* __restrict__ hout,
                                            float bv0, float bv1, int wv, int lane) {
    const int quad = lane >> 4, col = lane & 15;
    float4v acc0 = {bv0, bv0, bv0, bv0};
    float4v acc1 = {bv1, bv1, bv1, bv1};
    const unsigned short* arow = hin + col * SH;          // A: m = lane&15 (path row)
#pragma unroll
    for (int ks = 0; ks < 8; ++ks) {
        short8 a = *(const short8*)(arow + ks * 32 + quad * 8);
        acc0 = __builtin_amdgcn_mfma_f32_16x16x32_bf16(a, wf[ks], acc0, 0, 0, 0);
        acc1 = __builtin_amdgcn_mfma_f32_16x16x32_bf16(a, wf[8 + ks], acc1, 0, 0, 0);
    }
    // C/D layout: col = lane&15, row p = quad*4 + reg (m89-verified)
#pragma unroll
    for (int r = 0; r < 4; ++r) {
        const int p = quad * 4 + r;
        hout[p * SH + (wv * 2 + 0) * 16 + col] = f2bf(fmaxf(acc0[r], 0.0f));
        hout[p * SH + (wv * 2 + 1) * 16 + col] = f2bf(fmaxf(acc1[r], 0.0f));
    }
}

__global__ __launch_bounds__(NT, 4)
void lv_kernel(const float* __restrict__ W0, const float* __restrict__ b0,
               const float* __restrict__ b1, const float* __restrict__ b2,
               const float* __restrict__ b3,
               const float* __restrict__ obs_init, const float* __restrict__ feature_init,
               const float* __restrict__ tn_store, const float* __restrict__ x1_store,
               const float* __restrict__ x2_store, const float* __restrict__ path_seed,
               const unsigned short* __restrict__ wt,
               float* __restrict__ out) {
    __shared__ unsigned short hA[MROWS * SH];
    __shared__ unsigned short hB[MROWS * SH];
    __shared__ __align__(16) unsigned short w3l[4096];   // W3 fragments
    __shared__ float xs[PB][8];
    __shared__ float o3[MROWS][5];
    __shared__ __align__(16) float pbuf[PB * 202];       // path output buffer
    __shared__ __align__(16) float mbuf[PB * 200];       // mu output buffer
    __shared__ __align__(16) float sbuf[PB * 400];       // sigma output buffer

    const int tid = threadIdx.x;
    const int lane = tid & 63;
    const int wv = tid >> 6;            // wave 0..7
    const int quad = lane >> 4;
    const int col = lane & 15;
    const int pbase = blockIdx.x * PB;

    const float DTf = 0.1f;
    const float SQ = 0.31622776601683794f;  // sqrt(0.1)

    const unsigned short* Wt1 = wt;
    const unsigned short* Wt2 = wt + 65536;
    const unsigned short* Wt3 = wt + 131072;

    // ---- per-wave weight fragments into registers (once): 128 VGPRs ----
    short8 wf1[16], wf2[16];
#pragma unroll
    for (int cg2 = 0; cg2 < 2; ++cg2) {
#pragma unroll
        for (int ks = 0; ks < 8; ++ks) {
            const int idx = (((wv * 2 + cg2) * 8 + ks) * 64 + lane) * 8;
            wf1[cg2 * 8 + ks] = *(const short8*)(Wt1 + idx);
            wf2[cg2 * 8 + ks] = *(const short8*)(Wt2 + idx);
        }
    }
    // stage W3 fragments into LDS (8192 B, one float4 per thread)
    ((float4*)w3l)[tid] = ((const float4*)Wt3)[tid];

    // step-invariant hoists
    const float bv1a = b1[(wv * 2 + 0) * 16 + col];
    const float bv1b = b1[(wv * 2 + 1) * 16 + col];
    const float bv2a = b2[(wv * 2 + 0) * 16 + col];
    const float bv2b = b2[(wv * 2 + 1) * 16 + col];
    const float b3c = (col < 5) ? b3[col] : 0.0f;

    // layer-0 thread roles: path = tid>>6 (8 paths), 4 cols at c0 (coalesced W0)
    const int l0p = tid >> 6;
    const int c0 = (tid & 63) * 4;
    const float4 b0v = ldg4(b0 + c0);

    float tval = feature_init[0];  // t0
    float st0 = 0.0f, st1 = 0.0f;  // per-path state, lanes 0..7 of wave 0

    if (tid < PB) {
        const int p = tid, gp = pbase + p;
        st0 = obs_init[gp * 2 + 0];
        st1 = obs_init[gp * 2 + 1];
        xs[p][0] = st0;
        xs[p][1] = st1;
#pragma unroll
        for (int f = 0; f < 6; ++f) xs[p][2 + f] = feature_init[gp * 6 + f];
        pbuf[p * 202 + 0] = st0;
        pbuf[p * 202 + 101] = st1;
    }
    __syncthreads();                          // weights/w3l/xs ready

    for (int t = 0; t < LT; ++t) {
        // prefetch this step's seeds + next step's scalar features (wave 0)
        float e0 = 0.0f, e1 = 0.0f, ftn = 0.0f, fx1 = 0.0f, fx2 = 0.0f;
        if (tid < PB) {
            const int gp = pbase + tid;
            e0 = path_seed[(size_t)t * PP * 2 + gp * 2 + 0];
            e1 = path_seed[(size_t)t * PP * 2 + gp * 2 + 1];
            if (t < LT - 1) {
                ftn = tn_store[t];
                fx1 = x1_store[t];
                fx2 = x2_store[t];
            }
        }

        // ---- layer 0: 8->256, fp32 VALU, write bf16 into hA rows 0..7 ----
        {
            const float4 xa = *(const float4*)&xs[l0p][0];
            const float4 xb = *(const float4*)&xs[l0p][4];
            const float xk[8] = {xa.x, xa.y, xa.z, xa.w, xb.x, xb.y, xb.z, xb.w};
            float a0 = b0v.x, a1 = b0v.y, a2 = b0v.z, a3 = b0v.w;
#pragma unroll
            for (int k = 0; k < 8; ++k) {
                const float4 w = ldg4(W0 + k * HH + c0);
                const float xv = xk[k];
                a0 = fmaf(xv, w.x, a0); a1 = fmaf(xv, w.y, a1);
                a2 = fmaf(xv, w.z, a2); a3 = fmaf(xv, w.w, a3);
            }
            short4v o;
            o[0] = (short)f2bf(fmaxf(a0, 0.0f));
            o[1] = (short)f2bf(fmaxf(a1, 0.0f));
            o[2] = (short)f2bf(fmaxf(a2, 0.0f));
            o[3] = (short)f2bf(fmaxf(a3, 0.0f));
            *(short4v*)&hA[l0p * SH + c0] = o;
        }
        __syncthreads();                       // B: h0 ready

        mfma256_reg(wf1, hA, hB, bv1a, bv1b, wv, lane);   // h1 = relu(h0 @ W1 + b1)
        __syncthreads();                       // C: h1 ready, hA dead
        mfma256_reg(wf2, hB, hA, bv2a, bv2b, wv, lane);   // h2 = relu(h1 @ W2 + b2)
        __syncthreads();                       // D: h2 ready

        // ---- layer 3 (wave 0 only): 256->5 via MFMA, W3 frags from LDS ----
        if (wv == 0) {
            float4v acc = {b3c, b3c, b3c, b3c};
            const unsigned short* arow = hA + col * SH;
#pragma unroll
            for (int ks = 0; ks < 8; ++ks) {
                short8 a = *(const short8*)(arow + ks * 32 + quad * 8);
                short8 b = *(const short8*)(w3l + (ks * 64 + lane) * 8);
                acc = __builtin_amdgcn_mfma_f32_16x16x32_bf16(a, b, acc, 0, 0, 0);
            }
            if (col < 5) {
#pragma unroll
                for (int r = 0; r < 4; ++r) o3[quad * 4 + r][col] = acc[r];
            }
            // o3 produced and consumed within wave 0 -> intra-wave ordering only

            if (tid < PB) {
                const int p = tid;
                const float mu0 = o3[p][0];
                const float mu1 = o3[p][1];
                const float s11 = softplus_f(o3[p][2]);
                const float s21 = o3[p][3];
                const float s22 = softplus_f(o3[p][4]);
                const float n0 = softplus_f(st0 + DTf * mu0 + SQ * (s11 * e0));
                const float n1 = softplus_f(st1 + DTf * mu1 + SQ * (s21 * e0 + s22 * e1));
                st0 = n0;
                st1 = n1;
                // outputs -> LDS buffers
                pbuf[p * 202 + (t + 1)] = n0;
                pbuf[p * 202 + 101 + (t + 1)] = n1;
                mbuf[p * 200 + t * 2 + 0] = mu0;
                mbuf[p * 200 + t * 2 + 1] = mu1;
                sbuf[p * 400 + t * 4 + 0] = s11;
                sbuf[p * 400 + t * 4 + 1] = 0.0f;
                sbuf[p * 400 + t * 4 + 2] = s21;
                sbuf[p * 400 + t * 4 + 3] = s22;
                // next step's input
                const float tnew = tval + DTf;
                xs[p][0] = n0; xs[p][1] = n1;
                xs[p][2] = tnew; xs[p][3] = ftn;
                xs[p][4] = fx1; xs[p][5] = fx2;
                xs[p][6] = fx1; xs[p][7] = fx2;
            }
        }
        tval += DTf;          // all lanes in lockstep (fp32 sequential, matches ref)
        __syncthreads();       // A: xs/st ready; hA free for next layer0
    }

    // ---- coalesced output write phase (pbuf flushed; barrier A above) ----
    float* __restrict__ pdst = out + (size_t)pbase * 202;
    float* __restrict__ mdst = out + (size_t)PP * 202 + (size_t)pbase * 200;
    float* __restrict__ sdst = out + (size_t)PP * 202 + (size_t)PP * 200 + (size_t)pbase * 400;
    for (int i = tid; i < PB * 202 / 4; i += NT) ((float4*)pdst)[i] = ((const float4*)pbuf)[i];
    for (int i = tid; i < PB * 200 / 4; i += NT) ((float4*)mdst)[i] = ((const float4*)mbuf)[i];
    for (int i = tid; i < PB * 400 / 4; i += NT) ((float4*)sdst)[i] = ((const float4*)sbuf)[i];
}

extern "C" void kernel_launch(void* const* d_in, const int* in_sizes, int n_in,
                              void* d_out, int out_size, void* d_ws, size_t ws_size,
                              hipStream_t stream) {
    (void)in_sizes; (void)n_in; (void)out_size; (void)ws_size;
    unsigned short* wt = (unsigned short*)d_ws;   // 135168 bf16 = 264 KB
    prep_weights<<<528, 256, 0, stream>>>(
        (const float*)d_in[2],   // W1
        (const float*)d_in[4],   // W2
        (const float*)d_in[6],   // W3
        wt);
    lv_kernel<<<PP / PB, NT, 0, stream>>>(
        (const float*)d_in[0],   // W0
        (const float*)d_in[1],   // b0
        (const float*)d_in[3],   // b1
        (const float*)d_in[5],   // b2
        (const float*)d_in[7],   // b3
        (const float*)d_in[8],   // obs_init
        (const float*)d_in[9],   // feature_init
        (const float*)d_in[10],  // tn_store
        (const float*)d_in[11],  // x1_store
        (const float*)d_in[12],  // x2_store
        (const float*)d_in[13],  // path_seed
        wt,
        (float*)d_out);
}

// Round 7
// 411.618 us; speedup vs baseline: 4.1208x; 4.1208x over previous
//
#include <hip/hip_runtime.h>
#include <math.h>

// LotkaVolterra neural-SDE rollout. P=4096, H=256, 100 sequential steps.
// R7 (on R5's register-weights + LDS-buffered-outputs structure, 1 block/CU):
//  - Layer3 + sampling REDUNDANT in all 8 waves (per-wave LDS scratch
//    transpose, state in lanes<16 registers of every wave) -> serial wave0
//    tail eliminated, barrier A eliminated (3 barriers/step via hA/hB/hC
//    rotation; ordering through barriers C/D).
//  - Layer0 for t>=1: path-independent part precomputed per step into
//    cfeat[t][col] by prologue (exact fp32 tval chain); layer0 = 2 FMAs from
//    __shfl-broadcast state + LDS W0 rows. No global loads, no xs LDS.
//  - Seeds + cfeat prefetched one step ahead into registers.
//  - __launch_bounds__(512,2): weights (128 AGPR) + 128 VGPR = 256 regs/wave,
//    2 waves/SIMD. (512,4) PROVEN FATAL in R6: spills weights -> 5.6GB scratch.

#define PP 4096
#define HH 256
#define LT 100
#define PB 16
#define SH 264          // bf16 LDS row stride: 528 B
#define NT 512

typedef __attribute__((ext_vector_type(8))) short short8;
typedef __attribute__((ext_vector_type(4))) float float4v;

__device__ __forceinline__ float softplus_f(float x) {
    return fmaxf(x, 0.0f) + log1pf(expf(-fabsf(x)));
}
__device__ __forceinline__ unsigned short f2bf(float f) {   // RNE fp32->bf16
    unsigned int u = __float_as_uint(f);
    u += 0x7fffu + ((u >> 16) & 1u);
    return (unsigned short)(u >> 16);
}
__device__ __forceinline__ float4 ldg4(const float* p) { return *(const float4*)p; }

// ---- prologue: weight fragments (blocks 0..527) + cfeat table (block 528) ----
// frag layout: wt[m*65536 + ((cg*8+ks)*64+lane)*8+j] = W[(ks*32+(lane>>4)*8+j)*256 + cg*16+(lane&15)]
// W3 region [131072,135168). cfeat[t][col] = b0[col] + sum_f feat_t[f]*W0[2+f][col], t=1..99.
__global__ void prep_weights(const float* __restrict__ W0, const float* __restrict__ b0,
                             const float* __restrict__ W1, const float* __restrict__ W2,
                             const float* __restrict__ W3,
                             const float* __restrict__ feature_init,
                             const float* __restrict__ tn_store,
                             const float* __restrict__ x1_store,
                             const float* __restrict__ x2_store,
                             unsigned short* __restrict__ wt,
                             float* __restrict__ cfeat) {
    const int b = blockIdx.x;
    if (b < 528) {
        const int i = b * 256 + threadIdx.x;
        if (i < 131072) {
            const int m = i >> 16;            // 0 = W1, 1 = W2
            const int ii = i & 65535;
            const int k = ii >> 8, n = ii & 255;
            const float* W = m ? W2 : W1;
            const float val = W[ii];
            const int ks = k >> 5, quad = (k >> 3) & 3, j = k & 7;
            const int cg = n >> 4, c = n & 15;
            const int lane = quad * 16 + c;
            wt[m * 65536 + ((cg * 8 + ks) * 64 + lane) * 8 + j] = f2bf(val);
        } else if (i < 135168) {
            const int ii = i - 131072;
            const int j = ii & 7, lane = (ii >> 3) & 63, ks = ii >> 9;
            const int k = ks * 32 + (lane >> 4) * 8 + j;
            const int n = lane & 15;
            wt[i] = (n < 5) ? f2bf(W3[k * 5 + n]) : (unsigned short)0;
        }
    } else {
        const int col = threadIdx.x;          // 256 threads
        float tval = feature_init[0];         // t0; fp32 chain matches ref
        const float w2c = W0[2 * 256 + col], w3c = W0[3 * 256 + col];
        const float w46 = W0[4 * 256 + col] + W0[6 * 256 + col];
        const float w57 = W0[5 * 256 + col] + W0[7 * 256 + col];
        const float bc = b0[col];
        for (int t = 1; t < LT; ++t) {
            tval += 0.1f;
            const float tn = tn_store[t - 1], x1 = x1_store[t - 1], x2 = x2_store[t - 1];
            cfeat[t * 256 + col] = bc + tval * w2c + tn * w3c + x1 * w46 + x2 * w57;
        }
    }
}

// 256->256 bf16 MFMA layer, B-fragments from registers (unchanged from R5).
__device__ __forceinline__ void mfma256_reg(const short8 (&wf)[16],
                                            const unsigned short* __restrict__ hin,
                                            unsigned short* __restrict__ hout,
                                            float bv0, float bv1, int wv, int lane) {
    const int quad = lane >> 4, col = lane & 15;
    float4v acc0 = {bv0, bv0, bv0, bv0};
    float4v acc1 = {bv1, bv1, bv1, bv1};
    const unsigned short* arow = hin + col * SH;          // A: m = lane&15 (path)
#pragma unroll
    for (int ks = 0; ks < 8; ++ks) {
        short8 a = *(const short8*)(arow + ks * 32 + quad * 8);
        acc0 = __builtin_amdgcn_mfma_f32_16x16x32_bf16(a, wf[ks], acc0, 0, 0, 0);
        acc1 = __builtin_amdgcn_mfma_f32_16x16x32_bf16(a, wf[8 + ks], acc1, 0, 0, 0);
    }
    // C/D layout: col = lane&15, row p = quad*4 + reg (m89-verified)
#pragma unroll
    for (int r = 0; r < 4; ++r) {
        const int p = quad * 4 + r;
        hout[p * SH + (wv * 2 + 0) * 16 + col] = f2bf(fmaxf(acc0[r], 0.0f));
        hout[p * SH + (wv * 2 + 1) * 16 + col] = f2bf(fmaxf(acc1[r], 0.0f));
    }
}

__global__ __launch_bounds__(NT, 2)
void lv_kernel(const float* __restrict__ W0, const float* __restrict__ b0,
               const float* __restrict__ b1, const float* __restrict__ b2,
               const float* __restrict__ b3,
               const float* __restrict__ obs_init, const float* __restrict__ feature_init,
               const float* __restrict__ path_seed,
               const unsigned short* __restrict__ wt,
               const float* __restrict__ cfeat,
               float* __restrict__ out) {
    __shared__ unsigned short hA[PB * SH];
    __shared__ unsigned short hB[PB * SH];
    __shared__ unsigned short hC[PB * SH];
    __shared__ __align__(16) unsigned short w3l[4096];   // W3 fragments
    __shared__ __align__(16) float w0l[512];             // W0 rows 0,1
    __shared__ float xs[PB][8];                          // t0 only
    __shared__ float sc[8][16][5];                       // per-wave o3 scratch
    __shared__ __align__(16) float pbuf[PB * 202];
    __shared__ __align__(16) float mbuf[PB * 200];
    __shared__ __align__(16) float sbuf[PB * 400];

    const int tid = threadIdx.x;
    const int lane = tid & 63;
    const int wv = tid >> 6;            // wave 0..7
    const int quad = lane >> 4;
    const int col = lane & 15;
    const int pbase = blockIdx.x * PB;

    const float DTf = 0.1f;
    const float SQ = 0.31622776601683794f;  // sqrt(0.1)

    const unsigned short* Wt1 = wt;
    const unsigned short* Wt2 = wt + 65536;
    const unsigned short* Wt3 = wt + 131072;

    // ---- per-wave weight fragments into registers/AGPRs (once) ----
    short8 wf1[16], wf2[16];
#pragma unroll
    for (int cg2 = 0; cg2 < 2; ++cg2) {
#pragma unroll
        for (int ks = 0; ks < 8; ++ks) {
            const int idx = (((wv * 2 + cg2) * 8 + ks) * 64 + lane) * 8;
            wf1[cg2 * 8 + ks] = *(const short8*)(Wt1 + idx);
            wf2[cg2 * 8 + ks] = *(const short8*)(Wt2 + idx);
        }
    }
    ((float4*)w3l)[tid] = ((const float4*)Wt3)[tid];     // 512*16B = 8KB
    if (tid < 256) {
        w0l[tid] = W0[tid];
        w0l[256 + tid] = W0[256 + tid];
    }

    // step-invariant hoists
    const float bv1a = b1[(wv * 2 + 0) * 16 + col];
    const float bv1b = b1[(wv * 2 + 1) * 16 + col];
    const float bv2a = b2[(wv * 2 + 0) * 16 + col];
    const float bv2b = b2[(wv * 2 + 1) * 16 + col];
    const float b3c = (col < 5) ? b3[col] : 0.0f;

    // layer-0 mapping: path = tid>>5 (0..15), 8 cols at c0
    const int l0p = tid >> 5;
    const int c0 = (tid & 31) * 8;

    // per-path state, lanes 0..15 of EVERY wave (redundant)
    float st0 = 0.0f, st1 = 0.0f;
    if (lane < 16) {
        const int gp = pbase + lane;
        st0 = obs_init[gp * 2 + 0];
        st1 = obs_init[gp * 2 + 1];
    }
    if (tid < PB) {
        const int p = tid, gp = pbase + p;
        xs[p][0] = obs_init[gp * 2 + 0];
        xs[p][1] = obs_init[gp * 2 + 1];
#pragma unroll
        for (int f = 0; f < 6; ++f) xs[p][2 + f] = feature_init[gp * 6 + f];
        pbuf[p * 202 + 0] = xs[p][0];
        pbuf[p * 202 + 101] = xs[p][1];
    }
    __syncthreads();                          // weights/w3l/w0l/xs ready

    // ---- t=0 layer 0 (per-path features): one-time dense8 -> hA ----
    {
        const float4 b0a = ldg4(b0 + c0);
        const float4 b0b = ldg4(b0 + c0 + 4);
        const float4 xa = *(const float4*)&xs[l0p][0];
        const float4 xb = *(const float4*)&xs[l0p][4];
        const float xk[8] = {xa.x, xa.y, xa.z, xa.w, xb.x, xb.y, xb.z, xb.w};
        float a[8] = {b0a.x, b0a.y, b0a.z, b0a.w, b0b.x, b0b.y, b0b.z, b0b.w};
#pragma unroll
        for (int k = 0; k < 8; ++k) {
            const float4 wA = ldg4(W0 + k * HH + c0);
            const float4 wB = ldg4(W0 + k * HH + c0 + 4);
            const float xv = xk[k];
            a[0] = fmaf(xv, wA.x, a[0]); a[1] = fmaf(xv, wA.y, a[1]);
            a[2] = fmaf(xv, wA.z, a[2]); a[3] = fmaf(xv, wA.w, a[3]);
            a[4] = fmaf(xv, wB.x, a[4]); a[5] = fmaf(xv, wB.y, a[5]);
            a[6] = fmaf(xv, wB.z, a[6]); a[7] = fmaf(xv, wB.w, a[7]);
        }
        short8 o;
#pragma unroll
        for (int c = 0; c < 8; ++c) o[c] = (short)f2bf(fmaxf(a[c], 0.0f));
        *(short8*)&hA[l0p * SH + c0] = o;
    }
    // preload cfeat for t=1
    float4 cf0 = ldg4(cfeat + 256 + c0);
    float4 cf1 = ldg4(cfeat + 256 + c0 + 4);

    for (int t = 0; t < LT; ++t) {
        // seeds for this step (lanes<16 of every wave, redundant; L2 absorbs)
        float e0 = 0.0f, e1 = 0.0f;
        if (lane < 16) {
            const int gp = pbase + lane;
            e0 = path_seed[(size_t)t * PP * 2 + gp * 2 + 0];
            e1 = path_seed[(size_t)t * PP * 2 + gp * 2 + 1];
        }

        // ---- layer 0 (t>=1): 2 FMAs/col from shfl state + cfeat ----
        if (t > 0) {
            const float s0 = __shfl(st0, l0p);
            const float s1 = __shfl(st1, l0p);
            const float4 wa0 = *(const float4*)&w0l[c0];
            const float4 wa1 = *(const float4*)&w0l[c0 + 4];
            const float4 wb0 = *(const float4*)&w0l[256 + c0];
            const float4 wb1 = *(const float4*)&w0l[256 + c0 + 4];
            float a[8];
            a[0] = fmaf(s0, wa0.x, fmaf(s1, wb0.x, cf0.x));
            a[1] = fmaf(s0, wa0.y, fmaf(s1, wb0.y, cf0.y));
            a[2] = fmaf(s0, wa0.z, fmaf(s1, wb0.z, cf0.z));
            a[3] = fmaf(s0, wa0.w, fmaf(s1, wb0.w, cf0.w));
            a[4] = fmaf(s0, wa1.x, fmaf(s1, wb1.x, cf1.x));
            a[5] = fmaf(s0, wa1.y, fmaf(s1, wb1.y, cf1.y));
            a[6] = fmaf(s0, wa1.z, fmaf(s1, wb1.z, cf1.z));
            a[7] = fmaf(s0, wa1.w, fmaf(s1, wb1.w, cf1.w));
            short8 o;
#pragma unroll
            for (int c = 0; c < 8; ++c) o[c] = (short)f2bf(fmaxf(a[c], 0.0f));
            *(short8*)&hA[l0p * SH + c0] = o;
        }
        // prefetch next step's cfeat (used next iteration)
        {
            const int ti = (t + 1 < LT) ? (t + 1) : (LT - 1);
            const float* cp = cfeat + ti * 256 + c0;
            cf0 = ldg4(cp);
            cf1 = ldg4(cp + 4);
        }
        __syncthreads();                       // B: h0 (hA) ready

        mfma256_reg(wf1, hA, hB, bv1a, bv1b, wv, lane);   // h1 = relu(h0 @ W1 + b1)
        __syncthreads();                       // C: h1 (hB) ready
        mfma256_reg(wf2, hB, hC, bv2a, bv2b, wv, lane);   // h2 = relu(h1 @ W2 + b2)
        __syncthreads();                       // D: h2 (hC) ready
        // (no barrier A: hA rewrite at t+1 ordered after all hA reads via C/D)

        // ---- layer 3: ALL waves redundant, per-wave scratch transpose ----
        {
            float4v acc = {b3c, b3c, b3c, b3c};
            const unsigned short* arow = hC + col * SH;
#pragma unroll
            for (int ks = 0; ks < 8; ++ks) {
                short8 a = *(const short8*)(arow + ks * 32 + quad * 8);
                short8 b = *(const short8*)(w3l + (ks * 64 + lane) * 8);
                acc = __builtin_amdgcn_mfma_f32_16x16x32_bf16(a, b, acc, 0, 0, 0);
            }
            if (col < 5) {
#pragma unroll
                for (int r = 0; r < 4; ++r) sc[wv][quad * 4 + r][col] = acc[r];
            }
        }
        // intra-wave LDS ordering only (compiler lgkmcnt) — no barrier
        if (lane < 16) {
            const int p = lane;
            const float mu0 = sc[wv][p][0];
            const float mu1 = sc[wv][p][1];
            const float s11 = softplus_f(sc[wv][p][2]);
            const float s21 = sc[wv][p][3];
            const float s22 = softplus_f(sc[wv][p][4]);
            const float n0 = softplus_f(st0 + DTf * mu0 + SQ * (s11 * e0));
            const float n1 = softplus_f(st1 + DTf * mu1 + SQ * (s21 * e0 + s22 * e1));
            st0 = n0;
            st1 = n1;
            if (wv == 0) {
                pbuf[p * 202 + (t + 1)] = n0;
                pbuf[p * 202 + 101 + (t + 1)] = n1;
                mbuf[p * 200 + t * 2 + 0] = mu0;
                mbuf[p * 200 + t * 2 + 1] = mu1;
                sbuf[p * 400 + t * 4 + 0] = s11;
                sbuf[p * 400 + t * 4 + 1] = 0.0f;
                sbuf[p * 400 + t * 4 + 2] = s21;
                sbuf[p * 400 + t * 4 + 3] = s22;
            }
        }
    }
    __syncthreads();                           // pbuf/mbuf/sbuf complete

    // ---- coalesced output write phase ----
    float* __restrict__ pdst = out + (size_t)pbase * 202;
    float* __restrict__ mdst = out + (size_t)PP * 202 + (size_t)pbase * 200;
    float* __restrict__ sdst = out + (size_t)PP * 202 + (size_t)PP * 200 + (size_t)pbase * 400;
    for (int i = tid; i < PB * 202 / 4; i += NT) ((float4*)pdst)[i] = ((const float4*)pbuf)[i];
    for (int i = tid; i < PB * 200 / 4; i += NT) ((float4*)mdst)[i] = ((const float4*)mbuf)[i];
    for (int i = tid; i < PB * 400 / 4; i += NT) ((float4*)sdst)[i] = ((const float4*)sbuf)[i];
}

extern "C" void kernel_launch(void* const* d_in, const int* in_sizes, int n_in,
                              void* d_out, int out_size, void* d_ws, size_t ws_size,
                              hipStream_t stream) {
    (void)in_sizes; (void)n_in; (void)out_size; (void)ws_size;
    unsigned short* wt = (unsigned short*)d_ws;          // 135168 bf16 = 264 KB
    float* cfeat = (float*)(wt + 135168);                // 100*256 fp32 = 100 KB
    prep_weights<<<529, 256, 0, stream>>>(
        (const float*)d_in[0],   // W0
        (const float*)d_in[1],   // b0
        (const float*)d_in[2],   // W1
        (const float*)d_in[4],   // W2
        (const float*)d_in[6],   // W3
        (const float*)d_in[9],   // feature_init (t0)
        (const float*)d_in[10],  // tn_store
        (const float*)d_in[11],  // x1_store
        (const float*)d_in[12],  // x2_store
        wt, cfeat);
    lv_kernel<<<PP / PB, NT, 0, stream>>>(
        (const float*)d_in[0],   // W0
        (const float*)d_in[1],   // b0
        (const float*)d_in[3],   // b1
        (const float*)d_in[5],   // b2
        (const float*)d_in[7],   // b3
        (const float*)d_in[8],   // obs_init
        (const float*)d_in[9],   // feature_init
        (const float*)d_in[13],  // path_seed
        wt, cfeat,
        (float*)d_out);
}

// Round 8
// 371.289 us; speedup vs baseline: 4.5684x; 1.1086x over previous
//
#include <hip/hip_runtime.h>
#include <math.h>

// LotkaVolterra neural-SDE rollout. P=4096, H=256, 100 sequential steps.
// R8 (on R7): 16 waves/block (NT=1024), ONE col-group per wave per layer
// -> 64 weight VGPRs/wave (vs 128), total ~115 regs -> 4 waves/SIMD at
// 1 block/CU (R7 was stuck at 2 waves/SIMD with 252 regs). Fast softplus
// (__expf/__logf) cuts redundant sampling VALU ~3x. Layer0 = wave-per-path.
// Barriers stay at 3/step (B,C,D) with hA->hB->hC rotation (no barrier A).
// R6 lesson: watch FETCH_SIZE for spill (must stay ~3MB).

#define PP 4096
#define HH 256
#define LT 100
#define PB 16
#define SH 264          // bf16 LDS row stride: 528 B
#define NT 1024

typedef __attribute__((ext_vector_type(8))) short short8;
typedef __attribute__((ext_vector_type(4))) short short4v;
typedef __attribute__((ext_vector_type(4))) float float4v;

__device__ __forceinline__ float softplus_fast(float x) {
    // max(x,0) + log1p(exp(-|x|)) with fast exp/log (few-ulp; absmax margin 4x)
    const float e = __expf(-fabsf(x));
    return fmaxf(x, 0.0f) + __logf(1.0f + e);
}
__device__ __forceinline__ unsigned short f2bf(float f) {   // RNE fp32->bf16
    unsigned int u = __float_as_uint(f);
    u += 0x7fffu + ((u >> 16) & 1u);
    return (unsigned short)(u >> 16);
}
__device__ __forceinline__ float4 ldg4(const float* p) { return *(const float4*)p; }

// ---- prologue: weight fragments (blocks 0..527) + cfeat table (block 528) ----
// frag layout: wt[m*65536 + ((cg*8+ks)*64+lane)*8+j] = W[(ks*32+(lane>>4)*8+j)*256 + cg*16+(lane&15)]
// W3 region [131072,135168). cfeat[t][col] = b0[col] + sum_f feat_t[f]*W0[2+f][col], t=1..99.
__global__ void prep_weights(const float* __restrict__ W0, const float* __restrict__ b0,
                             const float* __restrict__ W1, const float* __restrict__ W2,
                             const float* __restrict__ W3,
                             const float* __restrict__ feature_init,
                             const float* __restrict__ tn_store,
                             const float* __restrict__ x1_store,
                             const float* __restrict__ x2_store,
                             unsigned short* __restrict__ wt,
                             float* __restrict__ cfeat) {
    const int b = blockIdx.x;
    if (b < 528) {
        const int i = b * 256 + threadIdx.x;
        if (i < 131072) {
            const int m = i >> 16;            // 0 = W1, 1 = W2
            const int ii = i & 65535;
            const int k = ii >> 8, n = ii & 255;
            const float* W = m ? W2 : W1;
            const float val = W[ii];
            const int ks = k >> 5, quad = (k >> 3) & 3, j = k & 7;
            const int cg = n >> 4, c = n & 15;
            const int lane = quad * 16 + c;
            wt[m * 65536 + ((cg * 8 + ks) * 64 + lane) * 8 + j] = f2bf(val);
        } else if (i < 135168) {
            const int ii = i - 131072;
            const int j = ii & 7, lane = (ii >> 3) & 63, ks = ii >> 9;
            const int k = ks * 32 + (lane >> 4) * 8 + j;
            const int n = lane & 15;
            wt[i] = (n < 5) ? f2bf(W3[k * 5 + n]) : (unsigned short)0;
        }
    } else {
        const int col = threadIdx.x;          // 256 threads
        float tval = feature_init[0];         // t0; fp32 chain matches ref
        const float w2c = W0[2 * 256 + col], w3c = W0[3 * 256 + col];
        const float w46 = W0[4 * 256 + col] + W0[6 * 256 + col];
        const float w57 = W0[5 * 256 + col] + W0[7 * 256 + col];
        const float bc = b0[col];
        for (int t = 1; t < LT; ++t) {
            tval += 0.1f;
            const float tn = tn_store[t - 1], x1 = x1_store[t - 1], x2 = x2_store[t - 1];
            cfeat[t * 256 + col] = bc + tval * w2c + tn * w3c + x1 * w46 + x2 * w57;
        }
    }
}

// 256->256 bf16 MFMA layer, ONE col-group (16 cols) per wave, B from registers.
__device__ __forceinline__ void mfma256_reg1(const short8 (&wf)[8],
                                             const unsigned short* __restrict__ hin,
                                             unsigned short* __restrict__ hout,
                                             float bv, int wv, int lane) {
    const int quad = lane >> 4, col = lane & 15;
    float4v acc = {bv, bv, bv, bv};
    const unsigned short* arow = hin + col * SH;          // A: m = lane&15 (path)
#pragma unroll
    for (int ks = 0; ks < 8; ++ks) {
        short8 a = *(const short8*)(arow + ks * 32 + quad * 8);
        acc = __builtin_amdgcn_mfma_f32_16x16x32_bf16(a, wf[ks], acc, 0, 0, 0);
    }
    // C/D layout: col = lane&15, row p = quad*4 + reg (m89-verified)
#pragma unroll
    for (int r = 0; r < 4; ++r) {
        hout[(quad * 4 + r) * SH + wv * 16 + col] = f2bf(fmaxf(acc[r], 0.0f));
    }
}

__global__ __launch_bounds__(NT, 1)
void lv_kernel(const float* __restrict__ W0, const float* __restrict__ b0,
               const float* __restrict__ b1, const float* __restrict__ b2,
               const float* __restrict__ b3,
               const float* __restrict__ obs_init, const float* __restrict__ feature_init,
               const float* __restrict__ path_seed,
               const unsigned short* __restrict__ wt,
               const float* __restrict__ cfeat,
               float* __restrict__ out) {
    __shared__ unsigned short hA[PB * SH];
    __shared__ unsigned short hB[PB * SH];
    __shared__ unsigned short hC[PB * SH];
    __shared__ __align__(16) unsigned short w3l[4096];   // W3 fragments
    __shared__ __align__(16) float w0l[512];             // W0 rows 0,1
    __shared__ float sc[16][16][5];                      // per-wave o3 scratch
    __shared__ __align__(16) float pbuf[PB * 202];
    __shared__ __align__(16) float mbuf[PB * 200];
    __shared__ __align__(16) float sbuf[PB * 400];

    const int tid = threadIdx.x;
    const int lane = tid & 63;
    const int wv = tid >> 6;            // wave 0..15; owns col-group wv (cols 16wv..16wv+15)
    const int quad = lane >> 4;
    const int col = lane & 15;
    const int pbase = blockIdx.x * PB;

    const float DTf = 0.1f;
    const float SQ = 0.31622776601683794f;  // sqrt(0.1)

    const unsigned short* Wt1 = wt;
    const unsigned short* Wt2 = wt + 65536;
    const unsigned short* Wt3 = wt + 131072;

    // ---- per-wave weight fragments (64 VGPRs total) ----
    short8 wf1[8], wf2[8];
#pragma unroll
    for (int ks = 0; ks < 8; ++ks) {
        const int idx = ((wv * 8 + ks) * 64 + lane) * 8;
        wf1[ks] = *(const short8*)(Wt1 + idx);
        wf2[ks] = *(const short8*)(Wt2 + idx);
    }
    if (tid < 512) ((float4*)w3l)[tid] = ((const float4*)Wt3)[tid];   // 8 KB
    if (tid < 512) w0l[tid] = W0[tid];                                // rows 0,1

    // step-invariant hoists (one col-group -> one bias each)
    const float bv1 = b1[wv * 16 + col];
    const float bv2 = b2[wv * 16 + col];
    const float b3c = (col < 5) ? b3[col] : 0.0f;

    // per-path state, lanes 0..15 of EVERY wave (redundant)
    float st0 = 0.0f, st1 = 0.0f;
    if (lane < 16) {
        const int gp = pbase + lane;
        st0 = obs_init[gp * 2 + 0];
        st1 = obs_init[gp * 2 + 1];
    }
    if (tid < PB) {
        const int p = tid, gp = pbase + p;
        pbuf[p * 202 + 0] = obs_init[gp * 2 + 0];
        pbuf[p * 202 + 101] = obs_init[gp * 2 + 1];
    }

    // ---- t=0 layer 0: wave wv handles path wv, 4 cols/lane (one-time, global W0) ----
    {
        const int gp = pbase + wv;
        float xk[8];
        xk[0] = obs_init[gp * 2 + 0];
        xk[1] = obs_init[gp * 2 + 1];
#pragma unroll
        for (int f = 0; f < 6; ++f) xk[2 + f] = feature_init[gp * 6 + f];
        const int c0 = lane * 4;
        const float4 bv = ldg4(b0 + c0);
        float a0 = bv.x, a1 = bv.y, a2 = bv.z, a3 = bv.w;
#pragma unroll
        for (int k = 0; k < 8; ++k) {
            const float4 w = ldg4(W0 + k * HH + c0);
            a0 = fmaf(xk[k], w.x, a0); a1 = fmaf(xk[k], w.y, a1);
            a2 = fmaf(xk[k], w.z, a2); a3 = fmaf(xk[k], w.w, a3);
        }
        short4v o;
        o[0] = (short)f2bf(fmaxf(a0, 0.0f));
        o[1] = (short)f2bf(fmaxf(a1, 0.0f));
        o[2] = (short)f2bf(fmaxf(a2, 0.0f));
        o[3] = (short)f2bf(fmaxf(a3, 0.0f));
        *(short4v*)&hA[wv * SH + c0] = o;
    }
    // preload cfeat for t=1 (4 cols per lane)
    float4 cf = ldg4(cfeat + 256 + lane * 4);

    for (int t = 0; t < LT; ++t) {
        // seeds for this step (lanes<16 of every wave, redundant; L1/L2 absorbs)
        float e0 = 0.0f, e1 = 0.0f;
        if (lane < 16) {
            const int gp = pbase + lane;
            e0 = path_seed[(size_t)t * PP * 2 + gp * 2 + 0];
            e1 = path_seed[(size_t)t * PP * 2 + gp * 2 + 1];
        }

        // ---- layer 0 (t>=1): wave wv = path wv; 2 FMAs/col from shfl state ----
        if (t > 0) {
            const float s0 = __shfl(st0, wv);
            const float s1 = __shfl(st1, wv);
            const int c0 = lane * 4;
            const float4 wa = *(const float4*)&w0l[c0];
            const float4 wb = *(const float4*)&w0l[256 + c0];
            short4v o;
            o[0] = (short)f2bf(fmaxf(fmaf(s0, wa.x, fmaf(s1, wb.x, cf.x)), 0.0f));
            o[1] = (short)f2bf(fmaxf(fmaf(s0, wa.y, fmaf(s1, wb.y, cf.y)), 0.0f));
            o[2] = (short)f2bf(fmaxf(fmaf(s0, wa.z, fmaf(s1, wb.z, cf.z)), 0.0f));
            o[3] = (short)f2bf(fmaxf(fmaf(s0, wa.w, fmaf(s1, wb.w, cf.w)), 0.0f));
            *(short4v*)&hA[wv * SH + c0] = o;
        }
        // prefetch next step's cfeat
        {
            const int ti = (t + 1 < LT) ? (t + 1) : (LT - 1);
            cf = ldg4(cfeat + ti * 256 + lane * 4);
        }
        __syncthreads();                       // B: h0 (hA) ready

        mfma256_reg1(wf1, hA, hB, bv1, wv, lane);   // h1 = relu(h0 @ W1 + b1)
        __syncthreads();                       // C: h1 (hB) ready
        mfma256_reg1(wf2, hB, hC, bv2, wv, lane);   // h2 = relu(h1 @ W2 + b2)
        __syncthreads();                       // D: h2 (hC) ready
        // (no barrier A: hA rewrite at t+1 is ordered after hA reads via C,D)

        // ---- layer 3 + sampling: redundant in every wave ----
        {
            float4v acc = {b3c, b3c, b3c, b3c};
            const unsigned short* arow = hC + col * SH;
#pragma unroll
            for (int ks = 0; ks < 8; ++ks) {
                short8 a = *(const short8*)(arow + ks * 32 + quad * 8);
                short8 b = *(const short8*)(w3l + (ks * 64 + lane) * 8);
                acc = __builtin_amdgcn_mfma_f32_16x16x32_bf16(a, b, acc, 0, 0, 0);
            }
            if (col < 5) {
#pragma unroll
                for (int r = 0; r < 4; ++r) sc[wv][quad * 4 + r][col] = acc[r];
            }
        }
        // intra-wave LDS ordering only (compiler lgkmcnt) — no barrier
        if (lane < 16) {
            const int p = lane;
            const float mu0 = sc[wv][p][0];
            const float mu1 = sc[wv][p][1];
            const float s11 = softplus_fast(sc[wv][p][2]);
            const float s21 = sc[wv][p][3];
            const float s22 = softplus_fast(sc[wv][p][4]);
            const float n0 = softplus_fast(st0 + DTf * mu0 + SQ * (s11 * e0));
            const float n1 = softplus_fast(st1 + DTf * mu1 + SQ * (s21 * e0 + s22 * e1));
            st0 = n0;
            st1 = n1;
            if (wv == 0) {
                pbuf[p * 202 + (t + 1)] = n0;
                pbuf[p * 202 + 101 + (t + 1)] = n1;
                mbuf[p * 200 + t * 2 + 0] = mu0;
                mbuf[p * 200 + t * 2 + 1] = mu1;
                sbuf[p * 400 + t * 4 + 0] = s11;
                sbuf[p * 400 + t * 4 + 1] = 0.0f;
                sbuf[p * 400 + t * 4 + 2] = s21;
                sbuf[p * 400 + t * 4 + 3] = s22;
            }
        }
    }
    __syncthreads();                           // pbuf/mbuf/sbuf complete

    // ---- coalesced output write phase ----
    float* __restrict__ pdst = out + (size_t)pbase * 202;
    float* __restrict__ mdst = out + (size_t)PP * 202 + (size_t)pbase * 200;
    float* __restrict__ sdst = out + (size_t)PP * 202 + (size_t)PP * 200 + (size_t)pbase * 400;
    for (int i = tid; i < PB * 202 / 4; i += NT) ((float4*)pdst)[i] = ((const float4*)pbuf)[i];
    for (int i = tid; i < PB * 200 / 4; i += NT) ((float4*)mdst)[i] = ((const float4*)mbuf)[i];
    for (int i = tid; i < PB * 400 / 4; i += NT) ((float4*)sdst)[i] = ((const float4*)sbuf)[i];
}

extern "C" void kernel_launch(void* const* d_in, const int* in_sizes, int n_in,
                              void* d_out, int out_size, void* d_ws, size_t ws_size,
                              hipStream_t stream) {
    (void)in_sizes; (void)n_in; (void)out_size; (void)ws_size;
    unsigned short* wt = (unsigned short*)d_ws;          // 135168 bf16 = 264 KB
    float* cfeat = (float*)(wt + 135168);                // 100*256 fp32 = 100 KB
    prep_weights<<<529, 256, 0, stream>>>(
        (const float*)d_in[0],   // W0
        (const float*)d_in[1],   // b0
        (const float*)d_in[2],   // W1
        (const float*)d_in[4],   // W2
        (const float*)d_in[6],   // W3
        (const float*)d_in[9],   // feature_init (t0)
        (const float*)d_in[10],  // tn_store
        (const float*)d_in[11],  // x1_store
        (const float*)d_in[12],  // x2_store
        wt, cfeat);
    lv_kernel<<<PP / PB, NT, 0, stream>>>(
        (const float*)d_in[0],   // W0
        (const float*)d_in[1],   // b0
        (const float*)d_in[3],   // b1
        (const float*)d_in[5],   // b2
        (const float*)d_in[7],   // b3
        (const float*)d_in[8],   // obs_init
        (const float*)d_in[9],   // feature_init
        (const float*)d_in[13],  // path_seed
        wt, cfeat,
        (float*)d_out);
}

// Round 9
// 351.309 us; speedup vs baseline: 4.8282x; 1.0569x over previous
//
#include <hip/hip_runtime.h>
#include <math.h>

// LotkaVolterra neural-SDE rollout. P=4096, H=256, 100 sequential steps.
// R9 (on R8): kernel was LDS-pipe-bound (512 b128/step = 6.1k cyc; half from
// layer-3 replicated in all 16 waves). Changes:
//  - Layer 3 + sampling: wave 0 ONLY. W3 fragments in registers (+32 VGPR,
//    total must stay <=128 for 4 waves/SIMD - watch FETCH for spill).
//  - Layer-3 MFMA chain split into 2 accumulators (shorter serial tail).
//  - State st[] in LDS; barrier E orders wave0's st write vs layer-0 reads.
//  - 4 barriers/step (B,C,D,E); hA/hB/hC rotation unchanged.
// LDS demand: ~264 b128/step (-48%).

#define PP 4096
#define HH 256
#define LT 100
#define PB 16
#define SH 264          // bf16 LDS row stride: 528 B
#define NT 1024

typedef __attribute__((ext_vector_type(8))) short short8;
typedef __attribute__((ext_vector_type(4))) short short4v;
typedef __attribute__((ext_vector_type(4))) float float4v;

__device__ __forceinline__ float softplus_fast(float x) {
    const float e = __expf(-fabsf(x));
    return fmaxf(x, 0.0f) + __logf(1.0f + e);
}
__device__ __forceinline__ unsigned short f2bf(float f) {   // RNE fp32->bf16
    unsigned int u = __float_as_uint(f);
    u += 0x7fffu + ((u >> 16) & 1u);
    return (unsigned short)(u >> 16);
}
__device__ __forceinline__ float4 ldg4(const float* p) { return *(const float4*)p; }

// ---- prologue: weight fragments (blocks 0..527) + cfeat table (block 528) ----
__global__ void prep_weights(const float* __restrict__ W0, const float* __restrict__ b0,
                             const float* __restrict__ W1, const float* __restrict__ W2,
                             const float* __restrict__ W3,
                             const float* __restrict__ feature_init,
                             const float* __restrict__ tn_store,
                             const float* __restrict__ x1_store,
                             const float* __restrict__ x2_store,
                             unsigned short* __restrict__ wt,
                             float* __restrict__ cfeat) {
    const int b = blockIdx.x;
    if (b < 528) {
        const int i = b * 256 + threadIdx.x;
        if (i < 131072) {
            const int m = i >> 16;            // 0 = W1, 1 = W2
            const int ii = i & 65535;
            const int k = ii >> 8, n = ii & 255;
            const float* W = m ? W2 : W1;
            const float val = W[ii];
            const int ks = k >> 5, quad = (k >> 3) & 3, j = k & 7;
            const int cg = n >> 4, c = n & 15;
            const int lane = quad * 16 + c;
            wt[m * 65536 + ((cg * 8 + ks) * 64 + lane) * 8 + j] = f2bf(val);
        } else if (i < 135168) {
            const int ii = i - 131072;
            const int j = ii & 7, lane = (ii >> 3) & 63, ks = ii >> 9;
            const int k = ks * 32 + (lane >> 4) * 8 + j;
            const int n = lane & 15;
            wt[i] = (n < 5) ? f2bf(W3[k * 5 + n]) : (unsigned short)0;
        }
    } else {
        const int col = threadIdx.x;          // 256 threads
        float tval = feature_init[0];         // t0; fp32 chain matches ref
        const float w2c = W0[2 * 256 + col], w3c = W0[3 * 256 + col];
        const float w46 = W0[4 * 256 + col] + W0[6 * 256 + col];
        const float w57 = W0[5 * 256 + col] + W0[7 * 256 + col];
        const float bc = b0[col];
        for (int t = 1; t < LT; ++t) {
            tval += 0.1f;
            const float tn = tn_store[t - 1], x1 = x1_store[t - 1], x2 = x2_store[t - 1];
            cfeat[t * 256 + col] = bc + tval * w2c + tn * w3c + x1 * w46 + x2 * w57;
        }
    }
}

// 256->256 bf16 MFMA layer, ONE col-group (16 cols) per wave, B from registers.
__device__ __forceinline__ void mfma256_reg1(const short8 (&wf)[8],
                                             const unsigned short* __restrict__ hin,
                                             unsigned short* __restrict__ hout,
                                             float bv, int wv, int lane) {
    const int quad = lane >> 4, col = lane & 15;
    float4v acc = {bv, bv, bv, bv};
    const unsigned short* arow = hin + col * SH;          // A: m = lane&15 (path)
#pragma unroll
    for (int ks = 0; ks < 8; ++ks) {
        short8 a = *(const short8*)(arow + ks * 32 + quad * 8);
        acc = __builtin_amdgcn_mfma_f32_16x16x32_bf16(a, wf[ks], acc, 0, 0, 0);
    }
    // C/D layout: col = lane&15, row p = quad*4 + reg (m89-verified)
#pragma unroll
    for (int r = 0; r < 4; ++r) {
        hout[(quad * 4 + r) * SH + wv * 16 + col] = f2bf(fmaxf(acc[r], 0.0f));
    }
}

__global__ __launch_bounds__(NT, 1)
void lv_kernel(const float* __restrict__ W0, const float* __restrict__ b0,
               const float* __restrict__ b1, const float* __restrict__ b2,
               const float* __restrict__ b3,
               const float* __restrict__ obs_init, const float* __restrict__ feature_init,
               const float* __restrict__ path_seed,
               const unsigned short* __restrict__ wt,
               const float* __restrict__ cfeat,
               float* __restrict__ out) {
    __shared__ unsigned short hA[PB * SH];
    __shared__ unsigned short hB[PB * SH];
    __shared__ unsigned short hC[PB * SH];
    __shared__ __align__(16) float w0l[512];             // W0 rows 0,1
    __shared__ float sc[16][5];                          // wave-0 o3 scratch
    __shared__ float st[PB][2];                          // path state
    __shared__ __align__(16) float pbuf[PB * 202];
    __shared__ __align__(16) float mbuf[PB * 200];
    __shared__ __align__(16) float sbuf[PB * 400];

    const int tid = threadIdx.x;
    const int lane = tid & 63;
    const int wv = tid >> 6;            // wave 0..15; owns col-group wv
    const int quad = lane >> 4;
    const int col = lane & 15;
    const int pbase = blockIdx.x * PB;

    const float DTf = 0.1f;
    const float SQ = 0.31622776601683794f;  // sqrt(0.1)

    const unsigned short* Wt1 = wt;
    const unsigned short* Wt2 = wt + 65536;
    const unsigned short* Wt3 = wt + 131072;

    // ---- per-wave weight fragments: wf1/wf2 32+32 VGPRs, wf3 +32 (wave0 use) ----
    short8 wf1[8], wf2[8], wf3[8];
#pragma unroll
    for (int ks = 0; ks < 8; ++ks) {
        const int idx = ((wv * 8 + ks) * 64 + lane) * 8;
        wf1[ks] = *(const short8*)(Wt1 + idx);
        wf2[ks] = *(const short8*)(Wt2 + idx);
        wf3[ks] = *(const short8*)(Wt3 + (ks * 64 + lane) * 8);
    }
    if (tid < 512) w0l[tid] = W0[tid];                   // rows 0,1

    // step-invariant hoists
    const float bv1 = b1[wv * 16 + col];
    const float bv2 = b2[wv * 16 + col];
    const float b3c = (col < 5) ? b3[col] : 0.0f;

    if (tid < PB) {
        const int p = tid, gp = pbase + p;
        pbuf[p * 202 + 0] = obs_init[gp * 2 + 0];
        pbuf[p * 202 + 101] = obs_init[gp * 2 + 1];
    }

    // ---- t=0 layer 0: wave wv handles path wv, 4 cols/lane (one-time) ----
    {
        const int gp = pbase + wv;
        float xk[8];
        xk[0] = obs_init[gp * 2 + 0];
        xk[1] = obs_init[gp * 2 + 1];
#pragma unroll
        for (int f = 0; f < 6; ++f) xk[2 + f] = feature_init[gp * 6 + f];
        const int c0 = lane * 4;
        const float4 bv = ldg4(b0 + c0);
        float a0 = bv.x, a1 = bv.y, a2 = bv.z, a3 = bv.w;
#pragma unroll
        for (int k = 0; k < 8; ++k) {
            const float4 w = ldg4(W0 + k * HH + c0);
            a0 = fmaf(xk[k], w.x, a0); a1 = fmaf(xk[k], w.y, a1);
            a2 = fmaf(xk[k], w.z, a2); a3 = fmaf(xk[k], w.w, a3);
        }
        short4v o;
        o[0] = (short)f2bf(fmaxf(a0, 0.0f));
        o[1] = (short)f2bf(fmaxf(a1, 0.0f));
        o[2] = (short)f2bf(fmaxf(a2, 0.0f));
        o[3] = (short)f2bf(fmaxf(a3, 0.0f));
        *(short4v*)&hA[wv * SH + c0] = o;
    }
    // preload cfeat for t=1 (4 cols per lane)
    float4 cf = ldg4(cfeat + 256 + lane * 4);

    for (int t = 0; t < LT; ++t) {
        // seeds for this step: wave 0 lanes<16 only (it does the sampling)
        float e0 = 0.0f, e1 = 0.0f;
        if (tid < PB) {
            const int gp = pbase + tid;
            e0 = path_seed[(size_t)t * PP * 2 + gp * 2 + 0];
            e1 = path_seed[(size_t)t * PP * 2 + gp * 2 + 1];
        }

        // ---- layer 0 (t>=1): wave wv = path wv; st from LDS (broadcast read) ----
        if (t > 0) {
            const float s0 = st[wv][0];
            const float s1 = st[wv][1];
            const int c0 = lane * 4;
            const float4 wa = *(const float4*)&w0l[c0];
            const float4 wb = *(const float4*)&w0l[256 + c0];
            short4v o;
            o[0] = (short)f2bf(fmaxf(fmaf(s0, wa.x, fmaf(s1, wb.x, cf.x)), 0.0f));
            o[1] = (short)f2bf(fmaxf(fmaf(s0, wa.y, fmaf(s1, wb.y, cf.y)), 0.0f));
            o[2] = (short)f2bf(fmaxf(fmaf(s0, wa.z, fmaf(s1, wb.z, cf.z)), 0.0f));
            o[3] = (short)f2bf(fmaxf(fmaf(s0, wa.w, fmaf(s1, wb.w, cf.w)), 0.0f));
            *(short4v*)&hA[wv * SH + c0] = o;
        }
        // prefetch next step's cfeat
        {
            const int ti = (t + 1 < LT) ? (t + 1) : (LT - 1);
            cf = ldg4(cfeat + ti * 256 + lane * 4);
        }
        __syncthreads();                       // B: h0 (hA) ready

        mfma256_reg1(wf1, hA, hB, bv1, wv, lane);   // h1 = relu(h0 @ W1 + b1)
        __syncthreads();                       // C: h1 (hB) ready
        mfma256_reg1(wf2, hB, hC, bv2, wv, lane);   // h2 = relu(h1 @ W2 + b2)
        __syncthreads();                       // D: h2 (hC) ready

        // ---- layer 3 + sampling: WAVE 0 ONLY (W3 from registers) ----
        if (wv == 0) {
            float4v accA = {b3c, b3c, b3c, b3c};
            float4v accB = {0.0f, 0.0f, 0.0f, 0.0f};
            const unsigned short* arow = hC + col * SH;
#pragma unroll
            for (int ks = 0; ks < 4; ++ks) {    // two chains of 4 (halve dep latency)
                short8 a0 = *(const short8*)(arow + ks * 32 + quad * 8);
                short8 a1 = *(const short8*)(arow + (ks + 4) * 32 + quad * 8);
                accA = __builtin_amdgcn_mfma_f32_16x16x32_bf16(a0, wf3[ks], accA, 0, 0, 0);
                accB = __builtin_amdgcn_mfma_f32_16x16x32_bf16(a1, wf3[ks + 4], accB, 0, 0, 0);
            }
            if (col < 5) {
#pragma unroll
                for (int r = 0; r < 4; ++r) sc[quad * 4 + r][col] = accA[r] + accB[r];
            }
            // intra-wave lgkmcnt ordering (same wave writes then reads sc)
            if (lane < 16) {
                const int p = lane;
                const float mu0 = sc[p][0];
                const float mu1 = sc[p][1];
                const float s11 = softplus_fast(sc[p][2]);
                const float s21 = sc[p][3];
                const float s22 = softplus_fast(sc[p][4]);
                const float ps0 = (t == 0) ? pbuf[p * 202 + 0] : st[p][0];
                const float ps1 = (t == 0) ? pbuf[p * 202 + 101] : st[p][1];
                const float n0 = softplus_fast(ps0 + DTf * mu0 + SQ * (s11 * e0));
                const float n1 = softplus_fast(ps1 + DTf * mu1 + SQ * (s21 * e0 + s22 * e1));
                st[p][0] = n0;
                st[p][1] = n1;
                pbuf[p * 202 + (t + 1)] = n0;
                pbuf[p * 202 + 101 + (t + 1)] = n1;
                mbuf[p * 200 + t * 2 + 0] = mu0;
                mbuf[p * 200 + t * 2 + 1] = mu1;
                sbuf[p * 400 + t * 4 + 0] = s11;
                sbuf[p * 400 + t * 4 + 1] = 0.0f;
                sbuf[p * 400 + t * 4 + 2] = s21;
                sbuf[p * 400 + t * 4 + 3] = s22;
            }
        }
        __syncthreads();                       // E: st ready for next layer0
    }

    // ---- coalesced output write phase ----
    float* __restrict__ pdst = out + (size_t)pbase * 202;
    float* __restrict__ mdst = out + (size_t)PP * 202 + (size_t)pbase * 200;
    float* __restrict__ sdst = out + (size_t)PP * 202 + (size_t)PP * 200 + (size_t)pbase * 400;
    for (int i = tid; i < PB * 202 / 4; i += NT) ((float4*)pdst)[i] = ((const float4*)pbuf)[i];
    for (int i = tid; i < PB * 200 / 4; i += NT) ((float4*)mdst)[i] = ((const float4*)mbuf)[i];
    for (int i = tid; i < PB * 400 / 4; i += NT) ((float4*)sdst)[i] = ((const float4*)sbuf)[i];
}

extern "C" void kernel_launch(void* const* d_in, const int* in_sizes, int n_in,
                              void* d_out, int out_size, void* d_ws, size_t ws_size,
                              hipStream_t stream) {
    (void)in_sizes; (void)n_in; (void)out_size; (void)ws_size;
    unsigned short* wt = (unsigned short*)d_ws;          // 135168 bf16 = 264 KB
    float* cfeat = (float*)(wt + 135168);                // 100*256 fp32 = 100 KB
    prep_weights<<<529, 256, 0, stream>>>(
        (const float*)d_in[0],   // W0
        (const float*)d_in[1],   // b0
        (const float*)d_in[2],   // W1
        (const float*)d_in[4],   // W2
        (const float*)d_in[6],   // W3
        (const float*)d_in[9],   // feature_init (t0)
        (const float*)d_in[10],  // tn_store
        (const float*)d_in[11],  // x1_store
        (const float*)d_in[12],  // x2_store
        wt, cfeat);
    lv_kernel<<<PP / PB, NT, 0, stream>>>(
        (const float*)d_in[0],   // W0
        (const float*)d_in[1],   // b0
        (const float*)d_in[3],   // b1
        (const float*)d_in[5],   // b2
        (const float*)d_in[7],   // b3
        (const float*)d_in[8],   // obs_init
        (const float*)d_in[9],   // feature_init
        (const float*)d_in[13],  // path_seed
        wt, cfeat,
        (float*)d_out);
}